// Round 1
// baseline (2502.506 us; speedup 1.0000x reference)
//
#include <hip/hip_runtime.h>
#include <math.h>

#define B_SZ 512
#define D_SZ 512
#define C_SZ 200000

static constexpr float kCOS_M  = 0.8775825618903728f;   // cos(0.5)
static constexpr float kSIN_M  = 0.479425538604203f;    // sin(0.5)
static constexpr float kTHRESH = -0.8775825618903728f;  // cos(pi - 0.5)
static constexpr float kMM     = 0.2397127693021015f;   // sin(pi-0.5)*0.5
static constexpr float kS      = 64.0f;
static constexpr float kEPS    = 1e-12f;

// ---------------- kernel 1: fn = l2norm(feats) ----------------
// one wave (64 lanes) per row; each lane handles 8 floats (2x float4)
__global__ void feat_norm_k(const float* __restrict__ feats, float* __restrict__ fn) {
  const int wave = threadIdx.x >> 6;
  const int lane = threadIdx.x & 63;
  const int row  = blockIdx.x * 4 + wave;
  const float* src = feats + row * D_SZ + lane * 8;
  float4 v0 = *(const float4*)(src);
  float4 v1 = *(const float4*)(src + 4);
  float ss = v0.x*v0.x + v0.y*v0.y + v0.z*v0.z + v0.w*v0.w
           + v1.x*v1.x + v1.y*v1.y + v1.z*v1.z + v1.w*v1.w;
#pragma unroll
  for (int off = 1; off < 64; off <<= 1) ss += __shfl_xor(ss, off);
  const float inv = 1.0f / fmaxf(sqrtf(ss), kEPS);
  v0.x *= inv; v0.y *= inv; v0.z *= inv; v0.w *= inv;
  v1.x *= inv; v1.y *= inv; v1.z *= inv; v1.w *= inv;
  float* dst = fn + row * D_SZ + lane * 8;
  *(float4*)(dst)     = v0;
  *(float4*)(dst + 4) = v1;
}

// ---------------- kernel 2: target_logit[b] (clipped) ----------------
// one wave per row b: dot(fn[b], w[lab]) and ||w[lab]||^2 in one pass
__global__ void target_k(const float* __restrict__ fn, const float* __restrict__ weight,
                         const int* __restrict__ labels, float* __restrict__ tl) {
  const int wave = threadIdx.x >> 6;
  const int lane = threadIdx.x & 63;
  const int b    = blockIdx.x * 4 + wave;
  const int lab  = labels[b];
  const float* fr = fn + b * D_SZ + lane * 8;
  const float* wr = weight + (size_t)lab * D_SZ + lane * 8;
  float4 f0 = *(const float4*)fr, f1 = *(const float4*)(fr + 4);
  float4 w0 = *(const float4*)wr, w1 = *(const float4*)(wr + 4);
  float dot = f0.x*w0.x + f0.y*w0.y + f0.z*w0.z + f0.w*w0.w
            + f1.x*w1.x + f1.y*w1.y + f1.z*w1.z + f1.w*w1.w;
  float wsq = w0.x*w0.x + w0.y*w0.y + w0.z*w0.z + w0.w*w0.w
            + w1.x*w1.x + w1.y*w1.y + w1.z*w1.z + w1.w*w1.w;
#pragma unroll
  for (int off = 1; off < 64; off <<= 1) {
    dot += __shfl_xor(dot, off);
    wsq += __shfl_xor(wsq, off);
  }
  if (lane == 0) {
    float cv = dot / fmaxf(sqrtf(wsq), kEPS);
    cv = fminf(fmaxf(cv, -1.0f), 1.0f);
    tl[b] = cv;
  }
}

// ---------------- kernel 3: t_new, cos_theta_m[b], final_target[b] ----------------
__global__ void scalar_k(const float* __restrict__ tl, const float* __restrict__ t_in,
                         float* __restrict__ ctm, float* __restrict__ ftl,
                         float* __restrict__ tnew) {
  __shared__ float wsum[8];
  const int tid = threadIdx.x;  // 512 threads
  const float v = tl[tid];
  float s = v;
#pragma unroll
  for (int off = 1; off < 64; off <<= 1) s += __shfl_xor(s, off);
  if ((tid & 63) == 0) wsum[tid >> 6] = s;
  __syncthreads();
  if (tid == 0) {
    float tot = 0.0f;
#pragma unroll
    for (int i = 0; i < 8; ++i) tot += wsum[i];
    tnew[0] = 0.01f * (tot * (1.0f / 512.0f)) + 0.99f * t_in[0];
  }
  const float sth = sqrtf(1.0f - v * v);
  const float cm  = v * kCOS_M - sth * kSIN_M;
  ctm[tid] = cm;
  ftl[tid] = (v > kTHRESH) ? cm : (v - kMM);
}

// ---------------- kernel 4: fused GEMM + curricular epilogue ----------------
// 128x128 tile, BK=32, 256 threads, 8x8 micro-tile (split 2x2 of 4x4 at
// offsets {0,64} to keep LDS reads 2-way-or-free on banks).
#define BM 128
#define BN 128
#define BK 32
#define LDP 4  // pad: row stride 132 floats = 528B (16B-aligned)

__global__ void gemm_k(const float* __restrict__ fn, const float* __restrict__ weight,
                       const int* __restrict__ labels, const float* __restrict__ ctm,
                       const float* __restrict__ ftl, const float* __restrict__ tnew,
                       float* __restrict__ out) {
  __shared__ __align__(16) float As[BK][BM + LDP];
  __shared__ __align__(16) float Bs[BK][BN + LDP];
  __shared__ float wsq_s[BN];
  __shared__ float ctm_s[BM];
  __shared__ float ftl_s[BM];
  __shared__ int   lab_s[BM];

  const int m0 = blockIdx.x * BM;   // x = m-tile (4 values): siblings that share a
  const int n0 = blockIdx.y * BN;   // weight tile are dispatch-adjacent -> L3 reuse
  const int t  = threadIdx.x;
  const int tx = t & 15;
  const int ty = t >> 4;

  if (t < BM) {
    ctm_s[t] = ctm[m0 + t];
    ftl_s[t] = ftl[m0 + t];
    lab_s[t] = labels[m0 + t];
  }
  if (t < BN) wsq_s[t] = 0.0f;

  float acc[8][8] = {};

  for (int k0 = 0; k0 < D_SZ; k0 += BK) {
    // stage A (fn): 128x32 floats = 1024 float4 / 256 threads = 4 each
#pragma unroll
    for (int i = 0; i < 4; ++i) {
      const int idx = t + i * 256;
      const int m = idx >> 3;        // 0..127
      const int q = idx & 7;         // 0..7  (q*4 = k offset)
      const float4 v = *(const float4*)(fn + (size_t)(m0 + m) * D_SZ + k0 + q * 4);
      As[q * 4 + 0][m] = v.x;
      As[q * 4 + 1][m] = v.y;
      As[q * 4 + 2][m] = v.z;
      As[q * 4 + 3][m] = v.w;
    }
    // stage B (weight rows = classes), guarded at the N edge
#pragma unroll
    for (int i = 0; i < 4; ++i) {
      const int idx = t + i * 256;
      const int n = idx >> 3;
      const int q = idx & 7;
      const int c = n0 + n;
      float4 v = make_float4(0.f, 0.f, 0.f, 0.f);
      if (c < C_SZ) v = *(const float4*)(weight + (size_t)c * D_SZ + k0 + q * 4);
      Bs[q * 4 + 0][n] = v.x;
      Bs[q * 4 + 1][n] = v.y;
      Bs[q * 4 + 2][n] = v.z;
      Bs[q * 4 + 3][n] = v.w;
    }
    __syncthreads();

    // fused ||w_c||^2 accumulation (waves 0-1 only; waves 2-3 go straight to FMA)
    if (t < BN) {
      float s = 0.0f;
#pragma unroll
      for (int kk = 0; kk < BK; ++kk) { const float b = Bs[kk][t]; s += b * b; }
      wsq_s[t] += s;
    }

    // main FMA loop: 64 FMA per kk per thread
#pragma unroll
    for (int kk = 0; kk < BK; ++kk) {
      const float4 a0 = *(const float4*)&As[kk][ty * 4];
      const float4 a1 = *(const float4*)&As[kk][64 + ty * 4];
      const float4 b0 = *(const float4*)&Bs[kk][tx * 4];
      const float4 b1 = *(const float4*)&Bs[kk][64 + tx * 4];
      const float a[8]  = {a0.x, a0.y, a0.z, a0.w, a1.x, a1.y, a1.z, a1.w};
      const float bb[8] = {b0.x, b0.y, b0.z, b0.w, b1.x, b1.y, b1.z, b1.w};
#pragma unroll
      for (int i = 0; i < 8; ++i)
#pragma unroll
        for (int j = 0; j < 8; ++j)
          acc[i][j] = fmaf(a[i], bb[j], acc[i][j]);
    }
    __syncthreads();
  }

  // ---------------- fused curricular epilogue ----------------
  const float tn = tnew[0];
#pragma unroll
  for (int i = 0; i < 8; ++i) {
    const int lr = ((i >> 2) * 64) + ty * 4 + (i & 3);  // local row
    const int m  = m0 + lr;
    const float ctmb = ctm_s[lr];
    const float ftlb = ftl_s[lr];
    const int   lb   = lab_s[lr];
    float* orow = out + (size_t)m * C_SZ;
#pragma unroll
    for (int ci = 0; ci < 2; ++ci) {
      const int lc0 = ci * 64 + tx * 4;
      const int c0  = n0 + lc0;
      if (c0 >= C_SZ) continue;  // C%4==0 -> whole quad in or out
      float r[4];
#pragma unroll
      for (int j = 0; j < 4; ++j) {
        const float ssv = wsq_s[lc0 + j];
        const float inv = 1.0f / fmaxf(sqrtf(ssv), kEPS);
        float cv = acc[i][ci * 4 + j] * inv;
        cv = fminf(fmaxf(cv, -1.0f), 1.0f);
        if (cv > ctmb) cv = cv * (tn + cv);   // hard-example reweight (mask)
        if (c0 + j == lb) cv = ftlb;          // label scatter
        r[j] = cv * kS;
      }
      *(float4*)(orow + c0) = make_float4(r[0], r[1], r[2], r[3]);
    }
  }
}

extern "C" void kernel_launch(void* const* d_in, const int* in_sizes, int n_in,
                              void* d_out, int out_size, void* d_ws, size_t ws_size,
                              hipStream_t stream) {
  const float* feats  = (const float*)d_in[0];
  const int*   labels = (const int*)d_in[1];
  const float* weight = (const float*)d_in[2];
  const float* t_in   = (const float*)d_in[3];
  float* out = (float*)d_out;

  float* ws   = (float*)d_ws;
  float* fn   = ws;                    // 512*512 floats
  float* tl   = fn + B_SZ * D_SZ;      // 512
  float* ctm  = tl + B_SZ;             // 512
  float* ftl  = ctm + B_SZ;            // 512
  float* tnew = ftl + B_SZ;            // 1

  feat_norm_k<<<B_SZ / 4, 256, 0, stream>>>(feats, fn);
  target_k<<<B_SZ / 4, 256, 0, stream>>>(fn, weight, labels, tl);
  scalar_k<<<1, B_SZ, 0, stream>>>(tl, t_in, ctm, ftl, tnew);

  dim3 grid(B_SZ / BM, (C_SZ + BN - 1) / BN);  // (4, 1563), m-fastest
  gemm_k<<<grid, 256, 0, stream>>>(fn, weight, labels, ctm, ftl, tnew, out);
}

// Round 2
// 1068.377 us; speedup vs baseline: 2.3423x; 2.3423x over previous
//
#include <hip/hip_runtime.h>
#include <math.h>

#define B_SZ 512
#define D_SZ 512
#define C_SZ 200000

static constexpr float kCOS_M  = 0.8775825618903728f;   // cos(0.5)
static constexpr float kSIN_M  = 0.479425538604203f;    // sin(0.5)
static constexpr float kTHRESH = -0.8775825618903728f;  // cos(pi - 0.5)
static constexpr float kMM     = 0.2397127693021015f;   // sin(pi-0.5)*0.5
static constexpr float kS      = 64.0f;
static constexpr float kEPS    = 1e-12f;

typedef __attribute__((ext_vector_type(8))) short short8;   // 8 bf16 = 4 VGPR
typedef __attribute__((ext_vector_type(4))) float f32x4;
typedef unsigned int u32;
typedef unsigned short u16;

// fp32 -> bf16 round-to-nearest-even (inputs are finite & small; no NaN path)
__device__ __forceinline__ u16 f2bf(float f) {
  u32 u = __float_as_uint(f);
  return (u16)((u + 0x7FFFu + ((u >> 16) & 1u)) >> 16);
}
__device__ __forceinline__ float bf2f(u16 h) {
  return __uint_as_float(((u32)h) << 16);
}
__device__ __forceinline__ uint4 pack8(const u16* h) {
  uint4 p;
  p.x = (u32)h[0] | ((u32)h[1] << 16);
  p.y = (u32)h[2] | ((u32)h[3] << 16);
  p.z = (u32)h[4] | ((u32)h[5] << 16);
  p.w = (u32)h[6] | ((u32)h[7] << 16);
  return p;
}

// async global->LDS, 16B per lane; LDS dest = wave-uniform base + lane*16 (HW)
__device__ __forceinline__ void async16(void* lds_base, const void* g_perlane) {
  __builtin_amdgcn_global_load_lds(
      (const __attribute__((address_space(1))) u32*)g_perlane,
      (__attribute__((address_space(3))) u32*)lds_base, 16, 0, 0);
}

// ---------- kernel 1: fn = l2norm(feats) -> swizzled bf16 hi/lo A-image ----------
// img layout: tile(mt,ks) = 128 rows x 64 bf16 (128B rows), 16KB contiguous,
// 16B slot s stored at s ^ (row&7)  (LDS-image order for linear global_load_lds)
__global__ void feat_img_k(const float* __restrict__ feats,
                           unsigned char* __restrict__ img_hi,
                           unsigned char* __restrict__ img_lo) {
  const int wave = threadIdx.x >> 6, lane = threadIdx.x & 63;
  const int row  = blockIdx.x * 4 + wave;
  const float* src = feats + (size_t)row * D_SZ + lane * 8;
  float v[8];
  *(float4*)(v)     = *(const float4*)src;
  *(float4*)(v + 4) = *(const float4*)(src + 4);
  float ss = 0.f;
#pragma unroll
  for (int i = 0; i < 8; ++i) ss += v[i] * v[i];
#pragma unroll
  for (int off = 1; off < 64; off <<= 1) ss += __shfl_xor(ss, off);
  const float inv = 1.0f / fmaxf(sqrtf(ss), kEPS);
  u16 hh[8], ll[8];
#pragma unroll
  for (int i = 0; i < 8; ++i) {
    const float f = v[i] * inv;
    const u16 h = f2bf(f);
    hh[i] = h;
    ll[i] = f2bf(f - bf2f(h));
  }
  const int mt = row >> 7, r = row & 127;
  const int ks = lane >> 3, slot = lane & 7;
  const size_t off = (size_t)(mt * 8 + ks) * 16384 + r * 128 + ((slot ^ (r & 7)) << 4);
  *(uint4*)(img_hi + off) = pack8(hh);
  *(uint4*)(img_lo + off) = pack8(ll);
}

// ---------- kernel 2: target_logit[b] (clipped), norms fused ----------
__global__ void target_k(const float* __restrict__ feats, const float* __restrict__ weight,
                         const int* __restrict__ labels, float* __restrict__ tl) {
  const int wave = threadIdx.x >> 6, lane = threadIdx.x & 63;
  const int b   = blockIdx.x * 4 + wave;
  const int lab = labels[b];
  const float* fr = feats + (size_t)b * D_SZ + lane * 8;
  const float* wr = weight + (size_t)lab * D_SZ + lane * 8;
  float4 f0 = *(const float4*)fr, f1 = *(const float4*)(fr + 4);
  float4 w0 = *(const float4*)wr, w1 = *(const float4*)(wr + 4);
  float dot = f0.x*w0.x + f0.y*w0.y + f0.z*w0.z + f0.w*w0.w
            + f1.x*w1.x + f1.y*w1.y + f1.z*w1.z + f1.w*w1.w;
  float fsq = f0.x*f0.x + f0.y*f0.y + f0.z*f0.z + f0.w*f0.w
            + f1.x*f1.x + f1.y*f1.y + f1.z*f1.z + f1.w*f1.w;
  float wsq = w0.x*w0.x + w0.y*w0.y + w0.z*w0.z + w0.w*w0.w
            + w1.x*w1.x + w1.y*w1.y + w1.z*w1.z + w1.w*w1.w;
#pragma unroll
  for (int off = 1; off < 64; off <<= 1) {
    dot += __shfl_xor(dot, off);
    fsq += __shfl_xor(fsq, off);
    wsq += __shfl_xor(wsq, off);
  }
  if (lane == 0) {
    float cv = dot / (fmaxf(sqrtf(fsq), kEPS) * fmaxf(sqrtf(wsq), kEPS));
    tl[b] = fminf(fmaxf(cv, -1.0f), 1.0f);
  }
}

// ---------- kernel 3: t_new, cos_theta_m[b], final_target[b] ----------
__global__ void scalar_k(const float* __restrict__ tl, const float* __restrict__ t_in,
                         float* __restrict__ ctm, float* __restrict__ ftl,
                         float* __restrict__ tnew) {
  __shared__ float wsum[8];
  const int tid = threadIdx.x;  // 512 threads
  const float v = tl[tid];
  float s = v;
#pragma unroll
  for (int off = 1; off < 64; off <<= 1) s += __shfl_xor(s, off);
  if ((tid & 63) == 0) wsum[tid >> 6] = s;
  __syncthreads();
  if (tid == 0) {
    float tot = 0.0f;
#pragma unroll
    for (int i = 0; i < 8; ++i) tot += wsum[i];
    tnew[0] = 0.01f * (tot * (1.0f / 512.0f)) + 0.99f * t_in[0];
  }
  const float sth = sqrtf(1.0f - v * v);
  const float cm  = v * kCOS_M - sth * kSIN_M;
  ctm[tid] = cm;
  ftl[tid] = (v > kTHRESH) ? cm : (v - kMM);
}

// ---------- kernel 4: split-bf16 MFMA GEMM + curricular epilogue ----------
// 128x128 tile, BK=64, 4 waves (2x2), 16x16x32 bf16 MFMA, 3-product split.
#define BM 128
#define BN 128
#define NWG 6252      // 4 m-tiles * 1563 n-tiles
#define XQ 781        // NWG/8
#define XR 4          // NWG%8

__global__ __launch_bounds__(256, 2)
void gemm_k(const unsigned char* __restrict__ imgA_hi, const unsigned char* __restrict__ imgA_lo,
            const float* __restrict__ weight, const int* __restrict__ labels,
            const float* __restrict__ ctm, const float* __restrict__ ftl,
            const float* __restrict__ tnew, float* __restrict__ out) {
  __shared__ __align__(16) unsigned char Ah[16384];
  __shared__ __align__(16) unsigned char Al[16384];
  __shared__ __align__(16) unsigned char Bh[16384];
  __shared__ __align__(16) unsigned char Bl[16384];   // total 64 KB exactly

  // bijective XCD swizzle: same-XCD blocks iterate m fastest over a
  // contiguous n-tile range -> weight tile L2-resident per XCD
  const int orig = blockIdx.x;
  const int xcd = orig & 7, pos = orig >> 3;
  const int nid = (xcd < XR ? xcd * (XQ + 1) : XR * (XQ + 1) + (xcd - XR) * XQ) + pos;
  const int m0 = (nid & 3) * BM;
  const int n0 = (nid >> 2) * BN;

  const int t = threadIdx.x;
  const int wave = t >> 6, lane = t & 63;
  const int wr = wave >> 1, wc = wave & 1;   // 2x2 wave grid, 64x64 per wave
  const int lr = lane & 15, lhi = lane >> 4; // frag index / k-group

  // B staging map: pair p = t + 256*i (i=0..3): col n=p>>3 (8 threads/col), slot=p&7
  const int sn  = t >> 3;   // + 32*i
  const int ssl = t & 7;
  float wsqp[4] = {0.f, 0.f, 0.f, 0.f};

  f32x4 acc[4][4];
#pragma unroll
  for (int mf = 0; mf < 4; ++mf)
#pragma unroll
    for (int nf = 0; nf < 4; ++nf) acc[mf][nf] = (f32x4){0.f, 0.f, 0.f, 0.f};

  const size_t tb0 = (size_t)(m0 >> 7) * 8 * 16384;

  for (int ks = 0; ks < 8; ++ks) {
    // ---- B: global fp32 loads (reg-staged) ----
    float4 bv[4][2];
#pragma unroll
    for (int i = 0; i < 4; ++i) {
      const int c = n0 + sn + 32 * i;
      if (c < C_SZ) {
        const float* wp = weight + (size_t)c * D_SZ + ks * 64 + ssl * 8;
        bv[i][0] = *(const float4*)wp;
        bv[i][1] = *(const float4*)(wp + 4);
      } else {
        bv[i][0] = make_float4(0.f, 0.f, 0.f, 0.f);
        bv[i][1] = make_float4(0.f, 0.f, 0.f, 0.f);
      }
    }
    // ---- A: async global->LDS (pre-swizzled image, linear copy) ----
    {
      const size_t tb = tb0 + (size_t)ks * 16384;
#pragma unroll
      for (int j = 0; j < 4; ++j) {
        const int kb = wave * 4 + j;
        async16(Ah + kb * 1024, imgA_hi + tb + kb * 1024 + (size_t)lane * 16);
        async16(Al + kb * 1024, imgA_lo + tb + kb * 1024 + (size_t)lane * 16);
      }
    }
    // ---- B: convert fp32 -> bf16 hi/lo, fused ||w||^2, swizzled ds_write ----
#pragma unroll
    for (int i = 0; i < 4; ++i) {
      const int n = sn + 32 * i;
      float f[8];
      *(float4*)f       = bv[i][0];
      *(float4*)(f + 4) = bv[i][1];
      float s = 0.f;
      u16 hh[8], ll[8];
#pragma unroll
      for (int e = 0; e < 8; ++e) {
        s += f[e] * f[e];
        const u16 h = f2bf(f[e]);
        hh[e] = h;
        ll[e] = f2bf(f[e] - bf2f(h));
      }
      wsqp[i] += s;
      const int off = n * 128 + ((ssl ^ (n & 7)) << 4);
      *(uint4*)(Bh + off) = pack8(hh);
      *(uint4*)(Bl + off) = pack8(ll);
    }
    __syncthreads();   // drains vmcnt (A tiles) + lgkmcnt (B writes)

    // ---- compute: 96 MFMA / wave / K-step ----
#pragma unroll
    for (int km = 0; km < 2; ++km) {
      short8 a_h[4], a_l[4];
#pragma unroll
      for (int mf = 0; mf < 4; ++mf) {
        const int row = wr * 64 + mf * 16 + lr;
        const int off = row * 128 + (((km * 4 + lhi) ^ (row & 7)) << 4);
        a_h[mf] = *(const short8*)(Ah + off);
        a_l[mf] = *(const short8*)(Al + off);
      }
#pragma unroll
      for (int nf = 0; nf < 4; ++nf) {
        const int row = wc * 64 + nf * 16 + lr;
        const int off = row * 128 + (((km * 4 + lhi) ^ (row & 7)) << 4);
        const short8 b_h = *(const short8*)(Bh + off);
        const short8 b_l = *(const short8*)(Bl + off);
#pragma unroll
        for (int mf = 0; mf < 4; ++mf) {
          acc[mf][nf] = __builtin_amdgcn_mfma_f32_16x16x32_bf16(a_h[mf], b_h, acc[mf][nf], 0, 0, 0);
          acc[mf][nf] = __builtin_amdgcn_mfma_f32_16x16x32_bf16(a_h[mf], b_l, acc[mf][nf], 0, 0, 0);
          acc[mf][nf] = __builtin_amdgcn_mfma_f32_16x16x32_bf16(a_l[mf], b_h, acc[mf][nf], 0, 0, 0);
        }
      }
    }
    __syncthreads();
  }

  // ---- epilogue: alias small arrays onto Ah (done with tiles) ----
  float* wsq_s = (float*)Ah;            // [128]
  float* ctm_s = (float*)Ah + 128;      // [128]
  float* ftl_s = (float*)Ah + 256;      // [128]
  int*   lab_s = (int*)Ah + 384;        // [128]
  if (t < BM) {
    ctm_s[t] = ctm[m0 + t];
    ftl_s[t] = ftl[m0 + t];
    lab_s[t] = labels[m0 + t];
  }
#pragma unroll
  for (int i = 0; i < 4; ++i) {
    float s = wsqp[i];
    s += __shfl_xor(s, 1);
    s += __shfl_xor(s, 2);
    s += __shfl_xor(s, 4);
    if ((t & 7) == 0) wsq_s[sn + 32 * i] = s;
  }
  __syncthreads();

  const float tn = tnew[0];
#pragma unroll
  for (int nf = 0; nf < 4; ++nf) {
    const int ncl = wc * 64 + nf * 16 + lr;
    const int nc  = n0 + ncl;
    if (nc >= C_SZ) continue;
    const float inv = 1.0f / fmaxf(sqrtf(wsq_s[ncl]), kEPS);
#pragma unroll
    for (int mf = 0; mf < 4; ++mf) {
#pragma unroll
      for (int r = 0; r < 4; ++r) {
        const int mrl = wr * 64 + mf * 16 + lhi * 4 + r;
        float cv = acc[mf][nf][r] * inv;
        cv = fminf(fmaxf(cv, -1.0f), 1.0f);
        if (cv > ctm_s[mrl]) cv = cv * (tn + cv);     // hard-example reweight
        if (nc == lab_s[mrl]) cv = ftl_s[mrl];        // label scatter
        out[(size_t)(m0 + mrl) * C_SZ + nc] = cv * kS;
      }
    }
  }
}

extern "C" void kernel_launch(void* const* d_in, const int* in_sizes, int n_in,
                              void* d_out, int out_size, void* d_ws, size_t ws_size,
                              hipStream_t stream) {
  const float* feats  = (const float*)d_in[0];
  const int*   labels = (const int*)d_in[1];
  const float* weight = (const float*)d_in[2];
  const float* t_in   = (const float*)d_in[3];
  float* out = (float*)d_out;

  unsigned char* ws = (unsigned char*)d_ws;
  unsigned char* imgA_hi = ws;                 // 512 KB (4 mt x 8 ks x 16 KB)
  unsigned char* imgA_lo = ws + 524288;        // 512 KB
  float* tl   = (float*)(ws + 1048576);        // 512
  float* ctm  = tl + B_SZ;                     // 512
  float* ftl  = ctm + B_SZ;                    // 512
  float* tnew = ftl + B_SZ;                    // 1

  feat_img_k<<<B_SZ / 4, 256, 0, stream>>>(feats, imgA_hi, imgA_lo);
  target_k<<<B_SZ / 4, 256, 0, stream>>>(feats, weight, labels, tl);
  scalar_k<<<1, B_SZ, 0, stream>>>(tl, t_in, ctm, ftl, tnew);
  gemm_k<<<NWG, 256, 0, stream>>>(imgA_hi, imgA_lo, weight, labels, ctm, ftl, tnew, out);
}